// Round 1
// baseline (2209.093 us; speedup 1.0000x reference)
//
#include <hip/hip_runtime.h>

// 2-layer GCN (PyG GCNConv semantics), fp32.
// out1[n] = relu( dinv[n]*(g1[n] + sum_{e:dst=n} ew_e*g1[src_e]) + b1 ),  g1 = dinv .* (x@W1)
// out [n] =       dinv[n]*(g2[n] + sum_{e:dst=n} ew_e*g2[src_e]) + b2,   g2 = dinv .* (out1@W2)
// deg[n] = 1 (self loop) + sum_{e:dst=n} ew_e ; dinv = rsqrt(deg)

#define TPB 256

__global__ __launch_bounds__(TPB) void k_deg_init(float* __restrict__ deg, int n) {
  int i = blockIdx.x * TPB + threadIdx.x;
  if (i < n) deg[i] = 1.0f;  // self-loop weight
}

__global__ __launch_bounds__(TPB) void k_deg_scatter(const int* __restrict__ dst,
                                                     const float* __restrict__ ew,
                                                     float* __restrict__ deg, int e) {
  int i = blockIdx.x * TPB + threadIdx.x;
  if (i < e) unsafeAtomicAdd(&deg[dst[i]], ew[i]);
}

__global__ __launch_bounds__(TPB) void k_dinv(float* __restrict__ deg, int n) {
  int i = blockIdx.x * TPB + threadIdx.x;
  if (i < n) {
    float d = deg[i];
    deg[i] = (d > 0.f) ? rsqrtf(d) : 0.f;
  }
}

// g1 = dinv .* (x @ W1); acc1 = g1 (self-loop init). 16 rows/block, 16 thr/row x 4 ch.
__global__ __launch_bounds__(TPB) void k_gemm1(const float* __restrict__ x,
                                               const float* __restrict__ W1,
                                               const float* __restrict__ dinv,
                                               float* __restrict__ g1,
                                               float* __restrict__ acc1, int n) {
  __shared__ float Wl[64 * 64];
  int t = threadIdx.x;
  {
    const float4* W4 = (const float4*)W1;
    float4* Wl4 = (float4*)Wl;
#pragma unroll
    for (int i = 0; i < 4; ++i) Wl4[t + TPB * i] = W4[t + TPB * i];
  }
  __syncthreads();
  int r = blockIdx.x * 16 + (t >> 4);
  if (r >= n) return;
  int c0 = (t & 15) << 2;
  const float4* xr = (const float4*)(x + (size_t)r * 64);
  float ax = 0.f, ay = 0.f, az = 0.f, aw = 0.f;
#pragma unroll
  for (int kk = 0; kk < 16; ++kk) {
    float4 xv = xr[kk];
    const float* w = &Wl[(kk * 4) * 64 + c0];
    float4 w0 = *(const float4*)(w);
    float4 w1 = *(const float4*)(w + 64);
    float4 w2 = *(const float4*)(w + 128);
    float4 w3 = *(const float4*)(w + 192);
    ax += xv.x * w0.x + xv.y * w1.x + xv.z * w2.x + xv.w * w3.x;
    ay += xv.x * w0.y + xv.y * w1.y + xv.z * w2.y + xv.w * w3.y;
    az += xv.x * w0.z + xv.y * w1.z + xv.z * w2.z + xv.w * w3.z;
    aw += xv.x * w0.w + xv.y * w1.w + xv.z * w2.w + xv.w * w3.w;
  }
  float dv = dinv[r];
  float4 o = {dv * ax, dv * ay, dv * az, dv * aw};
  *(float4*)(g1 + (size_t)r * 64 + c0) = o;
  *(float4*)(acc1 + (size_t)r * 64 + c0) = o;  // self-loop term
}

// acc1[dst] += ew * g1[src], 64 channels, 16 threads/edge x float4
__global__ __launch_bounds__(TPB) void k_scatter64(const int* __restrict__ si,
                                                   const int* __restrict__ di,
                                                   const float* __restrict__ ew,
                                                   const float* __restrict__ g,
                                                   float* __restrict__ acc, int e) {
  int t = blockIdx.x * TPB + threadIdx.x;
  int eid = t >> 4;
  if (eid >= e) return;
  int c0 = (t & 15) << 2;
  int s = si[eid], d = di[eid];
  float w = ew[eid];
  float4 gv = *(const float4*)(g + (size_t)s * 64 + c0);
  float* ap = acc + (size_t)d * 64 + c0;
  unsafeAtomicAdd(ap + 0, w * gv.x);
  unsafeAtomicAdd(ap + 1, w * gv.y);
  unsafeAtomicAdd(ap + 2, w * gv.z);
  unsafeAtomicAdd(ap + 3, w * gv.w);
}

// x2 = relu(dinv*acc1 + b1); g2 = dinv .* (x2 @ W2); out = g2 (self-loop init).
// 32 rows/block, 8 thr/row x 4 ch.
__global__ __launch_bounds__(TPB) void k_gemm2(const float* __restrict__ acc1,
                                               const float* __restrict__ W2,
                                               const float* __restrict__ b1,
                                               const float* __restrict__ dinv,
                                               float* __restrict__ g2,
                                               float* __restrict__ out, int n) {
  __shared__ float Wl[64 * 32];
  __shared__ float b1l[64];
  int t = threadIdx.x;
  {
    const float4* W4 = (const float4*)W2;
    float4* Wl4 = (float4*)Wl;
#pragma unroll
    for (int i = 0; i < 2; ++i) Wl4[t + TPB * i] = W4[t + TPB * i];
    if (t < 64) b1l[t] = b1[t];
  }
  __syncthreads();
  int r = blockIdx.x * 32 + (t >> 3);
  if (r >= n) return;
  int c0 = (t & 7) << 2;
  float dv = dinv[r];
  const float4* ar = (const float4*)(acc1 + (size_t)r * 64);
  float ax = 0.f, ay = 0.f, az = 0.f, aw = 0.f;
#pragma unroll
  for (int kk = 0; kk < 16; ++kk) {
    float4 v = ar[kk];
    float x0 = fmaxf(dv * v.x + b1l[4 * kk + 0], 0.f);
    float x1 = fmaxf(dv * v.y + b1l[4 * kk + 1], 0.f);
    float x2 = fmaxf(dv * v.z + b1l[4 * kk + 2], 0.f);
    float x3 = fmaxf(dv * v.w + b1l[4 * kk + 3], 0.f);
    const float* w = &Wl[(kk * 4) * 32 + c0];
    float4 w0 = *(const float4*)(w);
    float4 w1 = *(const float4*)(w + 32);
    float4 w2 = *(const float4*)(w + 64);
    float4 w3 = *(const float4*)(w + 96);
    ax += x0 * w0.x + x1 * w1.x + x2 * w2.x + x3 * w3.x;
    ay += x0 * w0.y + x1 * w1.y + x2 * w2.y + x3 * w3.y;
    az += x0 * w0.z + x1 * w1.z + x2 * w2.z + x3 * w3.z;
    aw += x0 * w0.w + x1 * w1.w + x2 * w2.w + x3 * w3.w;
  }
  float4 o = {dv * ax, dv * ay, dv * az, dv * aw};
  *(float4*)(g2 + (size_t)r * 32 + c0) = o;
  *(float4*)(out + (size_t)r * 32 + c0) = o;  // self-loop init
}

// out[dst] += ew * g2[src], 32 channels, 8 threads/edge x float4
__global__ __launch_bounds__(TPB) void k_scatter32(const int* __restrict__ si,
                                                   const int* __restrict__ di,
                                                   const float* __restrict__ ew,
                                                   const float* __restrict__ g,
                                                   float* __restrict__ acc, int e) {
  int t = blockIdx.x * TPB + threadIdx.x;
  int eid = t >> 3;
  if (eid >= e) return;
  int c0 = (t & 7) << 2;
  int s = si[eid], d = di[eid];
  float w = ew[eid];
  float4 gv = *(const float4*)(g + (size_t)s * 32 + c0);
  float* ap = acc + (size_t)d * 32 + c0;
  unsafeAtomicAdd(ap + 0, w * gv.x);
  unsafeAtomicAdd(ap + 1, w * gv.y);
  unsafeAtomicAdd(ap + 2, w * gv.z);
  unsafeAtomicAdd(ap + 3, w * gv.w);
}

// out = dinv*out + b2 (in place)
__global__ __launch_bounds__(TPB) void k_fin(float* __restrict__ out,
                                             const float* __restrict__ dinv,
                                             const float* __restrict__ b2, int n) {
  int t = blockIdx.x * TPB + threadIdx.x;
  int nid = t >> 3;
  if (nid >= n) return;
  int c0 = (t & 7) << 2;
  float dv = dinv[nid];
  float* p = out + (size_t)nid * 32 + c0;
  float4 v = *(float4*)p;
  float4 bb = *(const float4*)(b2 + c0);
  v.x = dv * v.x + bb.x;
  v.y = dv * v.y + bb.y;
  v.z = dv * v.z + bb.z;
  v.w = dv * v.w + bb.w;
  *(float4*)p = v;
}

extern "C" void kernel_launch(void* const* d_in, const int* in_sizes, int n_in,
                              void* d_out, int out_size, void* d_ws, size_t ws_size,
                              hipStream_t stream) {
  const float* x  = (const float*)d_in[0];
  const int* ei   = (const int*)d_in[1];
  const float* ew = (const float*)d_in[2];
  const float* W1 = (const float*)d_in[3];
  const float* b1 = (const float*)d_in[4];
  const float* W2 = (const float*)d_in[5];
  const float* b2 = (const float*)d_in[6];
  float* out = (float*)d_out;

  const int n = in_sizes[0] / 64;     // 100000
  const int e = in_sizes[1] / 2;      // 1600000
  const int* si = ei;                 // edge_index[0]
  const int* di = ei + e;             // edge_index[1]

  // workspace layout (floats)
  float* ws = (float*)d_ws;
  const size_t NPAD = 102400;             // dinv, padded
  float* dinv = ws;
  float* g1   = ws + NPAD;                // n*64
  float* acc1 = g1 + (size_t)n * 64;      // n*64
  float* g2   = acc1 + (size_t)n * 64;    // n*32

  int gb_n   = (n + TPB - 1) / TPB;
  int gb_e   = (e + TPB - 1) / TPB;
  int gb_g1  = (n + 15) / 16;
  int gb_s64 = (int)(((size_t)e * 16 + TPB - 1) / TPB);
  int gb_g2  = (n + 31) / 32;
  int gb_s32 = (int)(((size_t)e * 8 + TPB - 1) / TPB);
  int gb_fin = (int)(((size_t)n * 8 + TPB - 1) / TPB);

  k_deg_init<<<gb_n, TPB, 0, stream>>>(dinv, n);
  k_deg_scatter<<<gb_e, TPB, 0, stream>>>(di, ew, dinv, e);
  k_dinv<<<gb_n, TPB, 0, stream>>>(dinv, n);
  k_gemm1<<<gb_g1, TPB, 0, stream>>>(x, W1, dinv, g1, acc1, n);
  k_scatter64<<<gb_s64, TPB, 0, stream>>>(si, di, ew, g1, acc1, e);
  k_gemm2<<<gb_g2, TPB, 0, stream>>>(acc1, W2, b1, dinv, g2, out, n);
  k_scatter32<<<gb_s32, TPB, 0, stream>>>(si, di, ew, g2, out, e);
  k_fin<<<gb_fin, TPB, 0, stream>>>(out, dinv, b2, n);
}

// Round 2
// 694.139 us; speedup vs baseline: 3.1825x; 3.1825x over previous
//
#include <hip/hip_runtime.h>

// 2-layer GCN (PyG GCNConv), fp32 — CSR-gather formulation (no fp32 atomics).
//
// g1 = dinv .* (x@W1)                       [row-scale by dinv[src]]
// acc1[r] = g1[r] + sum_{e:dst=r} ew_e * g1[src_e]      (self-loop has ew=1)
// x2 = relu(dinv[r]*acc1[r] + b1)
// g2 = dinv .* (x2@W2)
// out[r] = dinv[r]*(g2[r] + sum_{e:dst=r} ew_e*g2[src_e]) + b2
//
// Edges are counting-sorted by dst into CSR (row_off, colpk=(src,ew)) once,
// reused by both gather layers. Only int atomics (hist/reorder) + one float
// atomic per edge (weighted degree) remain: 4.8M vs round-1's 153.6M.

#define TPB 256

__global__ __launch_bounds__(TPB) void k_init(float* __restrict__ degw,
                                              int* __restrict__ degi, int n) {
  int i = blockIdx.x * TPB + threadIdx.x;
  if (i < n) { degw[i] = 1.0f; degi[i] = 0; }  // self-loop weight; count excl. self
}

__global__ __launch_bounds__(TPB) void k_hist(const int* __restrict__ di,
                                              const float* __restrict__ ew,
                                              float* __restrict__ degw,
                                              int* __restrict__ degi, int e) {
  int i = blockIdx.x * TPB + threadIdx.x;
  if (i < e) {
    int d = di[i];
    unsafeAtomicAdd(&degw[d], ew[i]);
    atomicAdd(&degi[d], 1);
  }
}

__global__ __launch_bounds__(TPB) void k_dinv(float* __restrict__ degw, int n) {
  int i = blockIdx.x * TPB + threadIdx.x;
  if (i < n) {
    float d = degw[i];
    degw[i] = (d > 0.f) ? rsqrtf(d) : 0.f;
  }
}

// Single-block exclusive scan of degi[0..n) -> row_off[0..n]; also converts
// degi in place into the running-position array for the reorder pass.
__global__ __launch_bounds__(1024) void k_scan(int* __restrict__ degi,
                                               int* __restrict__ row_off,
                                               int n, int e) {
  __shared__ int ls[1024];
  int t = threadIdx.x;
  const int chunk = (n + 1023) / 1024;
  int lo = t * chunk;
  int hi = lo + chunk; if (hi > n) hi = n; if (lo > n) lo = n;
  int s = 0;
  for (int i = lo; i < hi; ++i) s += degi[i];
  ls[t] = s;
  __syncthreads();
  for (int off = 1; off < 1024; off <<= 1) {  // Hillis-Steele inclusive
    int v = (t >= off) ? ls[t - off] : 0;
    __syncthreads();
    ls[t] += v;
    __syncthreads();
  }
  int run = (t == 0) ? 0 : ls[t - 1];  // exclusive base for this chunk
  for (int i = lo; i < hi; ++i) {
    int d = degi[i];
    row_off[i] = run;
    degi[i] = run;  // becomes 'pos' for reorder
    run += d;
  }
  if (t == 0) row_off[n] = e;  // every edge has exactly one dst
}

__global__ __launch_bounds__(TPB) void k_reorder(const int* __restrict__ si,
                                                 const int* __restrict__ di,
                                                 const float* __restrict__ ew,
                                                 int* __restrict__ pos,
                                                 int2* __restrict__ colpk, int e) {
  int i = blockIdx.x * TPB + threadIdx.x;
  if (i < e) {
    int p = atomicAdd(&pos[di[i]], 1);
    colpk[p] = make_int2(si[i], __float_as_int(ew[i]));
  }
}

// g1 = dinv .* (x @ W1). 16 rows/block, 16 thr/row x 4 ch.
__global__ __launch_bounds__(TPB) void k_gemm1(const float* __restrict__ x,
                                               const float* __restrict__ W1,
                                               const float* __restrict__ dinv,
                                               float* __restrict__ g1, int n) {
  __shared__ float Wl[64 * 64];
  int t = threadIdx.x;
  {
    const float4* W4 = (const float4*)W1;
    float4* Wl4 = (float4*)Wl;
#pragma unroll
    for (int i = 0; i < 4; ++i) Wl4[t + TPB * i] = W4[t + TPB * i];
  }
  __syncthreads();
  int r = blockIdx.x * 16 + (t >> 4);
  if (r >= n) return;
  int c0 = (t & 15) << 2;
  const float4* xr = (const float4*)(x + (size_t)r * 64);
  float ax = 0.f, ay = 0.f, az = 0.f, aw = 0.f;
#pragma unroll
  for (int kk = 0; kk < 16; ++kk) {
    float4 xv = xr[kk];
    const float* w = &Wl[(kk * 4) * 64 + c0];
    float4 w0 = *(const float4*)(w);
    float4 w1 = *(const float4*)(w + 64);
    float4 w2 = *(const float4*)(w + 128);
    float4 w3 = *(const float4*)(w + 192);
    ax += xv.x * w0.x + xv.y * w1.x + xv.z * w2.x + xv.w * w3.x;
    ay += xv.x * w0.y + xv.y * w1.y + xv.z * w2.y + xv.w * w3.y;
    az += xv.x * w0.z + xv.y * w1.z + xv.z * w2.z + xv.w * w3.z;
    aw += xv.x * w0.w + xv.y * w1.w + xv.z * w2.w + xv.w * w3.w;
  }
  float dv = dinv[r];
  float4 o = {dv * ax, dv * ay, dv * az, dv * aw};
  *(float4*)(g1 + (size_t)r * 64 + c0) = o;
}

// acc1[r] = g1[r] + sum_j ew_j * g1[src_j]. 16 thr/node x float4, 16 nodes/block.
__global__ __launch_bounds__(TPB) void k_gather64(const float* __restrict__ g1,
                                                  const int2* __restrict__ colpk,
                                                  const int* __restrict__ row_off,
                                                  float* __restrict__ acc, int n) {
  int t = threadIdx.x;
  int r = blockIdx.x * 16 + (t >> 4);
  if (r >= n) return;
  int c0 = (t & 15) << 2;
  float4 a = *(const float4*)(g1 + (size_t)r * 64 + c0);  // self-loop (ew=1)
  int jb = row_off[r], je = row_off[r + 1];
  int j = jb;
  for (; j + 1 < je; j += 2) {
    int2 p0 = colpk[j], p1 = colpk[j + 1];
    float w0 = __int_as_float(p0.y), w1 = __int_as_float(p1.y);
    float4 u = *(const float4*)(g1 + (size_t)p0.x * 64 + c0);
    float4 v = *(const float4*)(g1 + (size_t)p1.x * 64 + c0);
    a.x += w0 * u.x + w1 * v.x;
    a.y += w0 * u.y + w1 * v.y;
    a.z += w0 * u.z + w1 * v.z;
    a.w += w0 * u.w + w1 * v.w;
  }
  if (j < je) {
    int2 p0 = colpk[j];
    float w0 = __int_as_float(p0.y);
    float4 u = *(const float4*)(g1 + (size_t)p0.x * 64 + c0);
    a.x += w0 * u.x; a.y += w0 * u.y; a.z += w0 * u.z; a.w += w0 * u.w;
  }
  *(float4*)(acc + (size_t)r * 64 + c0) = a;
}

// x2 = relu(dinv*acc1 + b1); g2 = dinv .* (x2 @ W2). 32 rows/block, 8 thr/row.
__global__ __launch_bounds__(TPB) void k_gemm2(const float* __restrict__ acc1,
                                               const float* __restrict__ W2,
                                               const float* __restrict__ b1,
                                               const float* __restrict__ dinv,
                                               float* __restrict__ g2, int n) {
  __shared__ float Wl[64 * 32];
  __shared__ float b1l[64];
  int t = threadIdx.x;
  {
    const float4* W4 = (const float4*)W2;
    float4* Wl4 = (float4*)Wl;
#pragma unroll
    for (int i = 0; i < 2; ++i) Wl4[t + TPB * i] = W4[t + TPB * i];
    if (t < 64) b1l[t] = b1[t];
  }
  __syncthreads();
  int r = blockIdx.x * 32 + (t >> 3);
  if (r >= n) return;
  int c0 = (t & 7) << 2;
  float dv = dinv[r];
  const float4* ar = (const float4*)(acc1 + (size_t)r * 64);
  float ax = 0.f, ay = 0.f, az = 0.f, aw = 0.f;
#pragma unroll
  for (int kk = 0; kk < 16; ++kk) {
    float4 v = ar[kk];
    float x0 = fmaxf(dv * v.x + b1l[4 * kk + 0], 0.f);
    float x1 = fmaxf(dv * v.y + b1l[4 * kk + 1], 0.f);
    float x2 = fmaxf(dv * v.z + b1l[4 * kk + 2], 0.f);
    float x3 = fmaxf(dv * v.w + b1l[4 * kk + 3], 0.f);
    const float* w = &Wl[(kk * 4) * 32 + c0];
    float4 w0 = *(const float4*)(w);
    float4 w1 = *(const float4*)(w + 32);
    float4 w2 = *(const float4*)(w + 64);
    float4 w3 = *(const float4*)(w + 96);
    ax += x0 * w0.x + x1 * w1.x + x2 * w2.x + x3 * w3.x;
    ay += x0 * w0.y + x1 * w1.y + x2 * w2.y + x3 * w3.y;
    az += x0 * w0.z + x1 * w1.z + x2 * w2.z + x3 * w3.z;
    aw += x0 * w0.w + x1 * w1.w + x2 * w2.w + x3 * w3.w;
  }
  float4 o = {dv * ax, dv * ay, dv * az, dv * aw};
  *(float4*)(g2 + (size_t)r * 32 + c0) = o;
}

// out[r] = dinv[r]*(g2[r] + sum_j ew_j*g2[src_j]) + b2. 8 thr/node x float4.
__global__ __launch_bounds__(TPB) void k_gather32(const float* __restrict__ g2,
                                                  const int2* __restrict__ colpk,
                                                  const int* __restrict__ row_off,
                                                  const float* __restrict__ dinv,
                                                  const float* __restrict__ b2,
                                                  float* __restrict__ out, int n) {
  int t = threadIdx.x;
  int r = blockIdx.x * 32 + (t >> 3);
  if (r >= n) return;
  int c0 = (t & 7) << 2;
  float4 a = *(const float4*)(g2 + (size_t)r * 32 + c0);  // self-loop
  int jb = row_off[r], je = row_off[r + 1];
  int j = jb;
  for (; j + 1 < je; j += 2) {
    int2 p0 = colpk[j], p1 = colpk[j + 1];
    float w0 = __int_as_float(p0.y), w1 = __int_as_float(p1.y);
    float4 u = *(const float4*)(g2 + (size_t)p0.x * 32 + c0);
    float4 v = *(const float4*)(g2 + (size_t)p1.x * 32 + c0);
    a.x += w0 * u.x + w1 * v.x;
    a.y += w0 * u.y + w1 * v.y;
    a.z += w0 * u.z + w1 * v.z;
    a.w += w0 * u.w + w1 * v.w;
  }
  if (j < je) {
    int2 p0 = colpk[j];
    float w0 = __int_as_float(p0.y);
    float4 u = *(const float4*)(g2 + (size_t)p0.x * 32 + c0);
    a.x += w0 * u.x; a.y += w0 * u.y; a.z += w0 * u.z; a.w += w0 * u.w;
  }
  float dv = dinv[r];
  float4 bb = *(const float4*)(b2 + c0);
  float4 o = {dv * a.x + bb.x, dv * a.y + bb.y, dv * a.z + bb.z, dv * a.w + bb.w};
  *(float4*)(out + (size_t)r * 32 + c0) = o;
}

extern "C" void kernel_launch(void* const* d_in, const int* in_sizes, int n_in,
                              void* d_out, int out_size, void* d_ws, size_t ws_size,
                              hipStream_t stream) {
  const float* x  = (const float*)d_in[0];
  const int* ei   = (const int*)d_in[1];
  const float* ew = (const float*)d_in[2];
  const float* W1 = (const float*)d_in[3];
  const float* b1 = (const float*)d_in[4];
  const float* W2 = (const float*)d_in[5];
  const float* b2 = (const float*)d_in[6];
  float* out = (float*)d_out;

  const int n = in_sizes[0] / 64;  // 100000
  const int e = in_sizes[1] / 2;   // 1600000
  const int* si = ei;
  const int* di = ei + e;

  // workspace layout (float-sized units); total ~65.2 MB
  float* ws = (float*)d_ws;
  const size_t NP = 100352;  // n padded to 256
  float* dinv    = ws;                               // [NP]
  float* g1      = ws + NP;                          // [n*64]; g2 reuses 1st half
  float* acc1    = g1 + (size_t)n * 64;              // [n*64]
  int*   degi    = (int*)(acc1 + (size_t)n * 64);    // [NP]   (becomes pos)
  int*   row_off = degi + NP;                        // [n+1, padded]
  int2*  colpk   = (int2*)(row_off + NP);            // [e] src+ew pairs
  float* g2      = g1;                               // reuse: g1 dead after gather64

  int gb_n  = (n + TPB - 1) / TPB;
  int gb_e  = (e + TPB - 1) / TPB;
  int gb_16 = (n + 15) / 16;
  int gb_32 = (n + 31) / 32;

  k_init<<<gb_n, TPB, 0, stream>>>(dinv, degi, n);
  k_hist<<<gb_e, TPB, 0, stream>>>(di, ew, dinv, degi, e);
  k_dinv<<<gb_n, TPB, 0, stream>>>(dinv, n);
  k_scan<<<1, 1024, 0, stream>>>(degi, row_off, n, e);
  k_reorder<<<gb_e, TPB, 0, stream>>>(si, di, ew, degi, colpk, e);
  k_gemm1<<<gb_16, TPB, 0, stream>>>(x, W1, dinv, g1, n);
  k_gather64<<<gb_16, TPB, 0, stream>>>(g1, colpk, row_off, acc1, n);
  k_gemm2<<<gb_32, TPB, 0, stream>>>(acc1, W2, b1, dinv, g2, n);
  k_gather32<<<gb_32, TPB, 0, stream>>>(g2, colpk, row_off, dinv, b2, out, n);
}

// Round 3
// 408.701 us; speedup vs baseline: 5.4052x; 1.6984x over previous
//
#include <hip/hip_runtime.h>

// 2-layer GCN (PyG GCNConv), fp32 — CSR-gather formulation (no fp32 atomics).
//
// g1 = dinv .* (x@W1)                       [row-scale by dinv[src]]
// acc1[r] = g1[r] + sum_{e:dst=r} ew_e * g1[src_e]      (self-loop has ew=1)
// x2 = relu(dinv[r]*acc1[r] + b1)
// g2 = dinv .* (x2@W2)
// out[r] = dinv[r]*(g2[r] + sum_{e:dst=r} ew_e*g2[src_e]) + b2
//
// Round-3: hierarchical 3-stage scan (round-2's single-block k_scan was 230us,
// one CU, latency-bound); weighted degree computed from CSR segments after
// reorder (kills the 1.6M float atomics in hist).

#define TPB 256

__global__ __launch_bounds__(TPB) void k_init(int* __restrict__ degi, int n) {
  int i = blockIdx.x * TPB + threadIdx.x;
  if (i < n) degi[i] = 0;
}

__global__ __launch_bounds__(TPB) void k_hist(const int* __restrict__ di,
                                              int* __restrict__ degi, int e) {
  int i = blockIdx.x * TPB + threadIdx.x;
  if (i < e) atomicAdd(&degi[di[i]], 1);
}

// ---- hierarchical exclusive scan of degi[0..n) ----
// stage 1: per-block (256 elems) sums
__global__ __launch_bounds__(TPB) void k_scan1(const int* __restrict__ degi,
                                               int* __restrict__ bsum, int n) {
  __shared__ int ls[TPB];
  int t = threadIdx.x;
  int i = blockIdx.x * TPB + t;
  ls[t] = (i < n) ? degi[i] : 0;
  __syncthreads();
  for (int off = TPB >> 1; off > 0; off >>= 1) {
    if (t < off) ls[t] += ls[t + off];
    __syncthreads();
  }
  if (t == 0) bsum[blockIdx.x] = ls[0];
}

// stage 2: single small block scans the <=512 block sums -> exclusive offsets
__global__ __launch_bounds__(512) void k_scan2(const int* __restrict__ bsum,
                                               int* __restrict__ bof, int nb) {
  __shared__ int ls[512];
  int t = threadIdx.x;
  int v = (t < nb) ? bsum[t] : 0;
  ls[t] = v;
  __syncthreads();
  for (int off = 1; off < 512; off <<= 1) {
    int u = (t >= off) ? ls[t - off] : 0;
    __syncthreads();
    ls[t] += u;
    __syncthreads();
  }
  if (t < nb) bof[t] = ls[t] - v;  // exclusive
}

// stage 3: in-block exclusive scan + block offset; writes row_off and pos
__global__ __launch_bounds__(TPB) void k_scan3(int* __restrict__ degi,
                                               const int* __restrict__ bof,
                                               int* __restrict__ row_off,
                                               int n, int e) {
  __shared__ int ls[TPB];
  int t = threadIdx.x;
  int i = blockIdx.x * TPB + t;
  int v = (i < n) ? degi[i] : 0;
  ls[t] = v;
  __syncthreads();
  for (int off = 1; off < TPB; off <<= 1) {
    int u = (t >= off) ? ls[t - off] : 0;
    __syncthreads();
    ls[t] += u;
    __syncthreads();
  }
  if (i < n) {
    int val = bof[blockIdx.x] + ls[t] - v;  // exclusive
    row_off[i] = val;
    degi[i] = val;  // running position for reorder
  }
  if (i == 0) row_off[n] = e;
}

__global__ __launch_bounds__(TPB) void k_reorder(const int* __restrict__ si,
                                                 const int* __restrict__ di,
                                                 const float* __restrict__ ew,
                                                 int* __restrict__ pos,
                                                 int2* __restrict__ colpk, int e) {
  int i = blockIdx.x * TPB + threadIdx.x;
  if (i < e) {
    int p = atomicAdd(&pos[di[i]], 1);
    colpk[p] = make_int2(si[i], __float_as_int(ew[i]));
  }
}

// dinv[r] = rsqrt(1 + sum of ew over row r) — contiguous CSR segment read
__global__ __launch_bounds__(TPB) void k_dinv(const int2* __restrict__ colpk,
                                              const int* __restrict__ row_off,
                                              float* __restrict__ dinv, int n) {
  int r = blockIdx.x * TPB + threadIdx.x;
  if (r >= n) return;
  int jb = row_off[r], je = row_off[r + 1];
  float s = 1.0f;  // self-loop
  for (int j = jb; j < je; ++j) s += __int_as_float(colpk[j].y);
  dinv[r] = rsqrtf(s);
}

// g1 = dinv .* (x @ W1). 16 rows/block, 16 thr/row x 4 ch.
__global__ __launch_bounds__(TPB) void k_gemm1(const float* __restrict__ x,
                                               const float* __restrict__ W1,
                                               const float* __restrict__ dinv,
                                               float* __restrict__ g1, int n) {
  __shared__ float Wl[64 * 64];
  int t = threadIdx.x;
  {
    const float4* W4 = (const float4*)W1;
    float4* Wl4 = (float4*)Wl;
#pragma unroll
    for (int i = 0; i < 4; ++i) Wl4[t + TPB * i] = W4[t + TPB * i];
  }
  __syncthreads();
  int r = blockIdx.x * 16 + (t >> 4);
  if (r >= n) return;
  int c0 = (t & 15) << 2;
  const float4* xr = (const float4*)(x + (size_t)r * 64);
  float ax = 0.f, ay = 0.f, az = 0.f, aw = 0.f;
#pragma unroll
  for (int kk = 0; kk < 16; ++kk) {
    float4 xv = xr[kk];
    const float* w = &Wl[(kk * 4) * 64 + c0];
    float4 w0 = *(const float4*)(w);
    float4 w1 = *(const float4*)(w + 64);
    float4 w2 = *(const float4*)(w + 128);
    float4 w3 = *(const float4*)(w + 192);
    ax += xv.x * w0.x + xv.y * w1.x + xv.z * w2.x + xv.w * w3.x;
    ay += xv.x * w0.y + xv.y * w1.y + xv.z * w2.y + xv.w * w3.y;
    az += xv.x * w0.z + xv.y * w1.z + xv.z * w2.z + xv.w * w3.z;
    aw += xv.x * w0.w + xv.y * w1.w + xv.z * w2.w + xv.w * w3.w;
  }
  float dv = dinv[r];
  float4 o = {dv * ax, dv * ay, dv * az, dv * aw};
  *(float4*)(g1 + (size_t)r * 64 + c0) = o;
}

// acc1[r] = g1[r] + sum_j ew_j * g1[src_j]. 16 thr/node x float4, 16 nodes/block.
__global__ __launch_bounds__(TPB) void k_gather64(const float* __restrict__ g1,
                                                  const int2* __restrict__ colpk,
                                                  const int* __restrict__ row_off,
                                                  float* __restrict__ acc, int n) {
  int t = threadIdx.x;
  int r = blockIdx.x * 16 + (t >> 4);
  if (r >= n) return;
  int c0 = (t & 15) << 2;
  float4 a = *(const float4*)(g1 + (size_t)r * 64 + c0);  // self-loop (ew=1)
  int jb = row_off[r], je = row_off[r + 1];
  int j = jb;
  for (; j + 1 < je; j += 2) {
    int2 p0 = colpk[j], p1 = colpk[j + 1];
    float w0 = __int_as_float(p0.y), w1 = __int_as_float(p1.y);
    float4 u = *(const float4*)(g1 + (size_t)p0.x * 64 + c0);
    float4 v = *(const float4*)(g1 + (size_t)p1.x * 64 + c0);
    a.x += w0 * u.x + w1 * v.x;
    a.y += w0 * u.y + w1 * v.y;
    a.z += w0 * u.z + w1 * v.z;
    a.w += w0 * u.w + w1 * v.w;
  }
  if (j < je) {
    int2 p0 = colpk[j];
    float w0 = __int_as_float(p0.y);
    float4 u = *(const float4*)(g1 + (size_t)p0.x * 64 + c0);
    a.x += w0 * u.x; a.y += w0 * u.y; a.z += w0 * u.z; a.w += w0 * u.w;
  }
  *(float4*)(acc + (size_t)r * 64 + c0) = a;
}

// x2 = relu(dinv*acc1 + b1); g2 = dinv .* (x2 @ W2). 32 rows/block, 8 thr/row.
__global__ __launch_bounds__(TPB) void k_gemm2(const float* __restrict__ acc1,
                                               const float* __restrict__ W2,
                                               const float* __restrict__ b1,
                                               const float* __restrict__ dinv,
                                               float* __restrict__ g2, int n) {
  __shared__ float Wl[64 * 32];
  __shared__ float b1l[64];
  int t = threadIdx.x;
  {
    const float4* W4 = (const float4*)W2;
    float4* Wl4 = (float4*)Wl;
#pragma unroll
    for (int i = 0; i < 2; ++i) Wl4[t + TPB * i] = W4[t + TPB * i];
    if (t < 64) b1l[t] = b1[t];
  }
  __syncthreads();
  int r = blockIdx.x * 32 + (t >> 3);
  if (r >= n) return;
  int c0 = (t & 7) << 2;
  float dv = dinv[r];
  const float4* ar = (const float4*)(acc1 + (size_t)r * 64);
  float ax = 0.f, ay = 0.f, az = 0.f, aw = 0.f;
#pragma unroll
  for (int kk = 0; kk < 16; ++kk) {
    float4 v = ar[kk];
    float x0 = fmaxf(dv * v.x + b1l[4 * kk + 0], 0.f);
    float x1 = fmaxf(dv * v.y + b1l[4 * kk + 1], 0.f);
    float x2 = fmaxf(dv * v.z + b1l[4 * kk + 2], 0.f);
    float x3 = fmaxf(dv * v.w + b1l[4 * kk + 3], 0.f);
    const float* w = &Wl[(kk * 4) * 32 + c0];
    float4 w0 = *(const float4*)(w);
    float4 w1 = *(const float4*)(w + 32);
    float4 w2 = *(const float4*)(w + 64);
    float4 w3 = *(const float4*)(w + 96);
    ax += x0 * w0.x + x1 * w1.x + x2 * w2.x + x3 * w3.x;
    ay += x0 * w0.y + x1 * w1.y + x2 * w2.y + x3 * w3.y;
    az += x0 * w0.z + x1 * w1.z + x2 * w2.z + x3 * w3.z;
    aw += x0 * w0.w + x1 * w1.w + x2 * w2.w + x3 * w3.w;
  }
  float4 o = {dv * ax, dv * ay, dv * az, dv * aw};
  *(float4*)(g2 + (size_t)r * 32 + c0) = o;
}

// out[r] = dinv[r]*(g2[r] + sum_j ew_j*g2[src_j]) + b2. 8 thr/node x float4.
__global__ __launch_bounds__(TPB) void k_gather32(const float* __restrict__ g2,
                                                  const int2* __restrict__ colpk,
                                                  const int* __restrict__ row_off,
                                                  const float* __restrict__ dinv,
                                                  const float* __restrict__ b2,
                                                  float* __restrict__ out, int n) {
  int t = threadIdx.x;
  int r = blockIdx.x * 32 + (t >> 3);
  if (r >= n) return;
  int c0 = (t & 7) << 2;
  float4 a = *(const float4*)(g2 + (size_t)r * 32 + c0);  // self-loop
  int jb = row_off[r], je = row_off[r + 1];
  int j = jb;
  for (; j + 1 < je; j += 2) {
    int2 p0 = colpk[j], p1 = colpk[j + 1];
    float w0 = __int_as_float(p0.y), w1 = __int_as_float(p1.y);
    float4 u = *(const float4*)(g2 + (size_t)p0.x * 32 + c0);
    float4 v = *(const float4*)(g2 + (size_t)p1.x * 32 + c0);
    a.x += w0 * u.x + w1 * v.x;
    a.y += w0 * u.y + w1 * v.y;
    a.z += w0 * u.z + w1 * v.z;
    a.w += w0 * u.w + w1 * v.w;
  }
  if (j < je) {
    int2 p0 = colpk[j];
    float w0 = __int_as_float(p0.y);
    float4 u = *(const float4*)(g2 + (size_t)p0.x * 32 + c0);
    a.x += w0 * u.x; a.y += w0 * u.y; a.z += w0 * u.z; a.w += w0 * u.w;
  }
  float dv = dinv[r];
  float4 bb = *(const float4*)(b2 + c0);
  float4 o = {dv * a.x + bb.x, dv * a.y + bb.y, dv * a.z + bb.z, dv * a.w + bb.w};
  *(float4*)(out + (size_t)r * 32 + c0) = o;
}

extern "C" void kernel_launch(void* const* d_in, const int* in_sizes, int n_in,
                              void* d_out, int out_size, void* d_ws, size_t ws_size,
                              hipStream_t stream) {
  const float* x  = (const float*)d_in[0];
  const int* ei   = (const int*)d_in[1];
  const float* ew = (const float*)d_in[2];
  const float* W1 = (const float*)d_in[3];
  const float* b1 = (const float*)d_in[4];
  const float* W2 = (const float*)d_in[5];
  const float* b2 = (const float*)d_in[6];
  float* out = (float*)d_out;

  const int n = in_sizes[0] / 64;  // 100000
  const int e = in_sizes[1] / 2;   // 1600000
  const int* si = ei;
  const int* di = ei + e;

  // workspace layout (float-sized units)
  float* ws = (float*)d_ws;
  const size_t NP = 100352;  // n padded to 256
  float* dinv    = ws;                               // [NP]
  float* g1      = ws + NP;                          // [n*64]; g2 reuses 1st half
  float* acc1    = g1 + (size_t)n * 64;              // [n*64]
  int*   degi    = (int*)(acc1 + (size_t)n * 64);    // [NP]   (becomes pos)
  int*   row_off = degi + NP;                        // [n+1, padded]
  int*   bsum    = row_off + NP;                     // [512]
  int*   bof     = bsum + 512;                       // [512]
  int2*  colpk   = (int2*)(bof + 512);               // [e] src+ew pairs
  float* g2      = g1;                               // reuse: g1 dead after gather64

  int gb_n  = (n + TPB - 1) / TPB;  // 391
  int gb_e  = (e + TPB - 1) / TPB;
  int gb_16 = (n + 15) / 16;
  int gb_32 = (n + 31) / 32;

  k_init<<<gb_n, TPB, 0, stream>>>(degi, n);
  k_hist<<<gb_e, TPB, 0, stream>>>(di, degi, e);
  k_scan1<<<gb_n, TPB, 0, stream>>>(degi, bsum, n);
  k_scan2<<<1, 512, 0, stream>>>(bsum, bof, gb_n);
  k_scan3<<<gb_n, TPB, 0, stream>>>(degi, bof, row_off, n, e);
  k_reorder<<<gb_e, TPB, 0, stream>>>(si, di, ew, degi, colpk, e);
  k_dinv<<<gb_n, TPB, 0, stream>>>(colpk, row_off, dinv, n);
  k_gemm1<<<gb_16, TPB, 0, stream>>>(x, W1, dinv, g1, n);
  k_gather64<<<gb_16, TPB, 0, stream>>>(g1, colpk, row_off, acc1, n);
  k_gemm2<<<gb_32, TPB, 0, stream>>>(acc1, W2, b1, dinv, g2, n);
  k_gather32<<<gb_32, TPB, 0, stream>>>(g2, colpk, row_off, dinv, b2, out, n);
}